// Round 6
// baseline (100.328 us; speedup 1.0000x reference)
//
#include <hip/hip_runtime.h>
#include <cstdint>

typedef _Float16 f16;
typedef _Float16 f16x2 __attribute__((ext_vector_type(2)));
typedef _Float16 f16x4 __attribute__((ext_vector_type(4)));
typedef _Float16 f16x8 __attribute__((ext_vector_type(8)));
typedef float    f32x4 __attribute__((ext_vector_type(4)));
typedef unsigned short u16;
typedef unsigned int   u32;
typedef unsigned long long u64;

#define LOG2E 1.44269504088896340736f

__device__ __forceinline__ f16x2 habs2(f16x2 v) {
    union { f16x2 h; u32 u; } x; x.h = v; x.u &= 0x7FFF7FFFu; return x.h;
}
#if __has_builtin(__builtin_amdgcn_fdot2)
__device__ __forceinline__ float fdot2f(f16x2 a, f16x2 b, float c) {
    return __builtin_amdgcn_fdot2(a, b, c, false);
}
#else
__device__ __forceinline__ float fdot2f(f16x2 a, f16x2 b, float c) {
    return c + (float)a.x * (float)b.x + (float)a.y * (float)b.y;
}
#endif
#if __has_builtin(__builtin_amdgcn_exp2f)
#define EXP2F __builtin_amdgcn_exp2f
#else
#define EXP2F exp2f
#endif

// ---------------------------------------------------------------------------
// K1: fused prep + projections (round-1/4 verified structure, unchanged).
// grid 256 x 384; block = 4 nodes; thread t -> (t>>7 selects W_l/W_r/W_v,
// t&127 is the output column).
// Outputs:
//   Wlh f16 [j][128]                 (o = h*32+d)
//   WrL f16 [4h][8c][1024 j][4 l]    (d = 4c+l; coalesced K2 phase-1 loads)
//   VL  f16 [4h][32 d][1024 j]       (MFMA B-frag: 8 contiguous j at fixed d)
//   AL  f32 [1024 i][4 h]  = sum_d 0.6*a_d*Wlh[i,h,d]
//   BR  f32 [4 h][1024 j]  = sum_d 0.6*a_d*Wrh[j,h,d]
// ---------------------------------------------------------------------------
__global__ __launch_bounds__(384) void k1_proj(
        const float* __restrict__ Wl, const float* __restrict__ Wr,
        const float* __restrict__ Wv, const float* __restrict__ h,
        const float* __restrict__ a_,
        f16* __restrict__ Wlh, f16* __restrict__ WrL, f16* __restrict__ VL,
        float* __restrict__ AL, float* __restrict__ BR) {
    __shared__ __align__(16) f16 hS[4][128];
    const int t    = threadIdx.x;
    const int i0   = blockIdx.x * 4;
    const int wsel = t >> 7, col = t & 127;
    const int lane = t & 63;

    for (int e = t; e < 512; e += 384)
        ((f16*)hS)[e] = (f16)h[i0 * 128 + e];

    const float* W = (wsel == 0) ? Wl : ((wsel == 1) ? Wr : Wv);
    f16x2 w2[64];
    #pragma unroll
    for (int c2 = 0; c2 < 64; c2++) {
        f16x2 v;
        v.x = (f16)W[(2 * c2) * 128 + col];
        v.y = (f16)W[(2 * c2 + 1) * 128 + col];
        w2[c2] = v;
    }
    const float asc = 0.6f * a_[col & 31];
    __syncthreads();

    #pragma unroll
    for (int i = 0; i < 4; i++) {
        const int j = i0 + i;
        const f16x2* hr = (const f16x2*)hS[i];
        float acc = 0.f;
        #pragma unroll
        for (int c2 = 0; c2 < 64; c2++) acc = fdot2f(hr[c2], w2[c2], acc);
        const f16 hv = (f16)acc;
        const int hh = col >> 5, dd = col & 31;
        if (wsel == 0) {
            Wlh[j * 128 + col] = hv;
        } else if (wsel == 1) {
            WrL[((hh * 8 + (dd >> 2)) * 1024 + j) * 4 + (dd & 3)] = hv;
        } else {
            VL[(hh * 32 + dd) * 1024 + j] = hv;
        }
        if (wsel < 2) {
            float part = asc * acc;
            #pragma unroll
            for (int off = 1; off < 32; off <<= 1) part += __shfl_xor(part, off);
            if ((lane & 31) == 0) {
                if (wsel == 0) AL[j * 4 + hh] = part;
                else           BR[hh * 1024 + j] = part;
            }
        }
    }
}

// ---------------------------------------------------------------------------
// K2: fused GATv2 attention + MFMA aggregation + LayerNorm + ReLU.
// grid 256 x 1024. Block = 4 nodes i. 16 waves: wave w -> (head hh = w&3,
// j-quarter q = w>>2). Same total VALU + L2 traffic as the 8-wave version,
// but 4 waves/SIMD give the scheduler work to fill load-latency and barrier
// skew (8-wave version ran 1 block/CU, 2 waves/SIMD, stalls fully exposed).
// Score: e[i,j,h] = AL[i,h] + BR[h,j] + sum_d (0.4 a_d)|Wlh+Wrh|
// Softmax: local quarter-max exp, 4-way scalar combine folded into lr.
// ---------------------------------------------------------------------------
__global__ __launch_bounds__(1024) void GATv2Layer_84447646974220_kernel(
        const f16* __restrict__ Wlh, const f16* __restrict__ WrL,
        const f16* __restrict__ VL,  const int* __restrict__ adj,
        const float* __restrict__ AL, const float* __restrict__ BR,
        const float* __restrict__ a_, const float* __restrict__ ln_g,
        const float* __restrict__ ln_b, float* __restrict__ out) {

    __shared__ __align__(16) f16 ep[4][4][1024];   // [head][row][j]  32768 B
    __shared__ float aggS[4][4][128];              // [qtr][row][col]  8192 B
    __shared__ float redM[4][4][4];                // [qtr][head][row]  256 B
    __shared__ float redS[4][4][4];
    __shared__ u64 amaskS[4][16];                  // [row][jword]      512 B

    const int t    = threadIdx.x;
    const int w    = t >> 6;        // 0..15
    const int lane = t & 63;
    const int hh   = w & 3;         // head
    const int q    = w >> 2;        // j-quarter (j in [q*256, q*256+256))
    const int i0   = blockIdx.x * 4;

    // ---- phase 0: adj -> bitmask (wave w: row w&3, words (w>>2)*4..+3) ----
    {
        const int r  = w & 3;
        const int w0 = q * 4;
        #pragma unroll
        for (int c = 0; c < 4; c++) {
            int av = adj[(i0 + r) * 1024 + (w0 + c) * 64 + lane];
            u64 m = __ballot(av != 0);
            if (lane == 0) amaskS[r][w0 + c] = m;
        }
    }

    // per-wave constants while the mask settles
    f16x2 q2[16];
    #pragma unroll
    for (int d2 = 0; d2 < 16; d2++) {
        f16x2 qq; qq.x = (f16)(0.4f * a_[2 * d2]); qq.y = (f16)(0.4f * a_[2 * d2 + 1]);
        q2[d2] = qq;
    }
    f16x2 wl2[4][16];
    float al[4];
    #pragma unroll
    for (int ii = 0; ii < 4; ii++) {
        const f16x2* src = (const f16x2*)(Wlh + (i0 + ii) * 128 + hh * 32);
        #pragma unroll
        for (int c2 = 0; c2 < 16; c2++) wl2[ii][c2] = src[c2];
        al[ii] = AL[(i0 + ii) * 4 + hh];          // wave-uniform broadcast
    }
    __syncthreads();   // amaskS ready

    // ---- phase 1: scores e[i][j] over this wave's quarter (4 jb blocks) ----
    float maxE[4];
    #pragma unroll
    for (int ii = 0; ii < 4; ii++) maxE[ii] = -__builtin_inff();

    #pragma unroll 2
    for (int jb = 0; jb < 4; jb++) {
        const int j = q * 256 + jb * 64 + lane;
        f16x4 wr[8];
        #pragma unroll
        for (int c = 0; c < 8; c++)
            wr[c] = *(const f16x4*)(WrL + ((hh * 8 + c) * 1024 + j) * 4);
        const float bj = BR[hh * 1024 + j];

        float e[4];
        #pragma unroll
        for (int ii = 0; ii < 4; ii++) e[ii] = al[ii];
        #pragma unroll
        for (int c = 0; c < 8; c++) {
            #pragma unroll
            for (int ii = 0; ii < 4; ii++) {
                f16x2 t0 = wl2[ii][2 * c]     + wr[c].lo;
                f16x2 t1 = wl2[ii][2 * c + 1] + wr[c].hi;
                e[ii] = fdot2f(q2[2 * c],     habs2(t0), e[ii]);
                e[ii] = fdot2f(q2[2 * c + 1], habs2(t1), e[ii]);
            }
        }
        #pragma unroll
        for (int ii = 0; ii < 4; ii++) {
            bool ok = (amaskS[ii][q * 4 + jb] >> lane) & 1ull;
            float v = ok ? (e[ii] + bj) : -__builtin_inff();
            maxE[ii] = fmaxf(maxE[ii], v);
            ep[hh][ii][j] = (f16)v;
        }
    }

    // ---- phase 2: LOCAL softmax over this quarter (no cross-wave wait) ----
    #pragma unroll
    for (int ii = 0; ii < 4; ii++) {
        float M = maxE[ii];
        #pragma unroll
        for (int off = 32; off > 0; off >>= 1) M = fmaxf(M, __shfl_xor(M, off));
        maxE[ii] = M;                 // wave-wide quarter max
    }
    #pragma unroll
    for (int ii = 0; ii < 4; ii++) {
        float Mk = fmaxf(maxE[ii], -3.0e38f);   // finite guard (all-masked qtr)
        f16x4 v0 = *(f16x4*)&ep[hh][ii][q * 256 + lane * 4];
        float pb[4], l = 0.f;
        #pragma unroll
        for (int e = 0; e < 4; e++) pb[e] = EXP2F(((float)v0[e] - Mk) * LOG2E);
        #pragma unroll
        for (int e = 0; e < 4; e++) { v0[e] = (f16)pb[e]; l += pb[e]; }
        *(f16x4*)&ep[hh][ii][q * 256 + lane * 4] = v0;
        #pragma unroll
        for (int off = 32; off > 0; off >>= 1) l += __shfl_xor(l, off);
        if (lane == 0) { redM[q][hh][ii] = maxE[ii]; redS[q][hh][ii] = l; }
    }
    __syncthreads();

    // 4-way cross-quarter combine: agg linear in p -> scale folds into lr
    float lr[4];
    #pragma unroll
    for (int ii = 0; ii < 4; ii++) {
        float M0 = redM[0][hh][ii], M1 = redM[1][hh][ii];
        float M2 = redM[2][hh][ii], M3 = redM[3][hh][ii];
        float M  = fmaxf(fmaxf(M0, M1), fmaxf(M2, M3));
        float s0 = EXP2F((M0 - M) * LOG2E);
        float s1 = EXP2F((M1 - M) * LOG2E);
        float s2 = EXP2F((M2 - M) * LOG2E);
        float s3 = EXP2F((M3 - M) * LOG2E);
        float l  = redS[0][hh][ii] * s0 + redS[1][hh][ii] * s1
                 + redS[2][hh][ii] * s2 + redS[3][hh][ii] * s3;
        float sq = (q == 0) ? s0 : ((q == 1) ? s1 : ((q == 2) ? s2 : s3));
        lr[ii] = sq / l;
    }

    // ---- phase 3: agg = p @ V via MFMA (2 jt tiles per wave) ----
    // A-frag: A[m=lane&15][k=(lane>>4)*8+jj]; rows 4..15 duplicate rows 0..3
    // (m3 = lane&3) — garbage C-rows discarded. B-frag: B[k][n=lane&15] from
    // VL[d=n][j=k] (contiguous j). C/D: col=lane&15, row=(lane>>4)*4+reg.
    f32x4 acc0 = {0.f, 0.f, 0.f, 0.f}, acc1 = {0.f, 0.f, 0.f, 0.f};
    const int q8  = (lane >> 4) << 3;
    const int m3  = lane & 3;
    const int n15 = lane & 15;

    #pragma unroll
    for (int jt2 = 0; jt2 < 2; jt2++) {
        int jt = q * 2 + jt2;
        #pragma unroll
        for (int kk = 0; kk < 4; kk++) {
            int ko = jt * 128 + kk * 32 + q8;
            f16x8 af = *(const f16x8*)&ep[hh][m3][ko];
            f16x8 b0 = *(const f16x8*)(VL + (hh * 32 + n15) * 1024 + ko);
            f16x8 b1 = *(const f16x8*)(VL + (hh * 32 + 16 + n15) * 1024 + ko);
            acc0 = __builtin_amdgcn_mfma_f32_16x16x32_f16(af, b0, acc0, 0, 0, 0);
            acc1 = __builtin_amdgcn_mfma_f32_16x16x32_f16(af, b1, acc1, 0, 0, 0);
        }
    }

    if (lane < 16) {
        #pragma unroll
        for (int r = 0; r < 4; r++) {
            aggS[q][r][hh * 32 + lane]      = acc0[r] * lr[r];
            aggS[q][r][hh * 32 + 16 + lane] = acc1[r] * lr[r];
        }
    }
    __syncthreads();

    // ---- phase 4: LayerNorm + ReLU (waves 0..3, one node-row each) ----
    if (w < 4) {
        float x0 = aggS[0][w][lane]      + aggS[1][w][lane]
                 + aggS[2][w][lane]      + aggS[3][w][lane];
        float x1 = aggS[0][w][lane + 64] + aggS[1][w][lane + 64]
                 + aggS[2][w][lane + 64] + aggS[3][w][lane + 64];
        float s = x0 + x1, sq = x0 * x0 + x1 * x1;
        #pragma unroll
        for (int off = 32; off > 0; off >>= 1) {
            s  += __shfl_xor(s, off);
            sq += __shfl_xor(sq, off);
        }
        float mean = s * (1.f / 128.f);
        float var  = sq * (1.f / 128.f) - mean * mean;
        float rs   = rsqrtf(var + 1e-5f);
        float y0 = fmaxf((x0 - mean) * rs * ln_g[lane]      + ln_b[lane],      0.f);
        float y1 = fmaxf((x1 - mean) * rs * ln_g[lane + 64] + ln_b[lane + 64], 0.f);
        out[(i0 + w) * 128 + lane]      = y0;
        out[(i0 + w) * 128 + 64 + lane] = y1;
    }
}

// ---------------------------------------------------------------------------
extern "C" void kernel_launch(void* const* d_in, const int* in_sizes, int n_in,
                              void* d_out, int out_size, void* d_ws, size_t ws_size,
                              hipStream_t stream) {
    const float* h   = (const float*)d_in[0];
    const int*   adj = (const int*)d_in[1];
    const float* Wl  = (const float*)d_in[2];
    const float* Wr  = (const float*)d_in[3];
    const float* Wv  = (const float*)d_in[4];
    const float* a_  = (const float*)d_in[5];
    const float* g_  = (const float*)d_in[6];
    const float* b_  = (const float*)d_in[7];
    float* out = (float*)d_out;

    char* ws = (char*)d_ws;
    f16*   Wlh = (f16*)(ws);                 // 1024*128 f16    = 262144 B
    f16*   WrL = (f16*)(ws + 262144);        // [4][8][1024][4] = 262144 B
    f16*   VL  = (f16*)(ws + 524288);        // [4][32][1024]   = 262144 B
    float* AL  = (float*)(ws + 786432);      // [1024][4] f32   =  16384 B
    float* BR  = (float*)(ws + 802816);      // [4][1024] f32   =  16384 B

    k1_proj<<<256, 384, 0, stream>>>(Wl, Wr, Wv, h, a_, Wlh, WrL, VL, AL, BR);
    GATv2Layer_84447646974220_kernel<<<256, 1024, 0, stream>>>(
        Wlh, WrL, VL, adj, AL, BR, a_, g_, b_, out);
}

// Round 7
// 94.866 us; speedup vs baseline: 1.0576x; 1.0576x over previous
//
#include <hip/hip_runtime.h>
#include <cstdint>

typedef _Float16 f16;
typedef _Float16 f16x2 __attribute__((ext_vector_type(2)));
typedef _Float16 f16x4 __attribute__((ext_vector_type(4)));
typedef _Float16 f16x8 __attribute__((ext_vector_type(8)));
typedef float    f32x4 __attribute__((ext_vector_type(4)));
typedef unsigned short u16;
typedef unsigned int   u32;

#define LOG2E 1.44269504088896340736f

__device__ __forceinline__ f16x2 habs2(f16x2 v) {
    union { f16x2 h; u32 u; } x; x.h = v; x.u &= 0x7FFF7FFFu; return x.h;
}
#if __has_builtin(__builtin_amdgcn_fdot2)
__device__ __forceinline__ float fdot2f(f16x2 a, f16x2 b, float c) {
    return __builtin_amdgcn_fdot2(a, b, c, false);
}
#else
__device__ __forceinline__ float fdot2f(f16x2 a, f16x2 b, float c) {
    return c + (float)a.x * (float)b.x + (float)a.y * (float)b.y;
}
#endif
#if __has_builtin(__builtin_amdgcn_exp2f)
#define EXP2F __builtin_amdgcn_exp2f
#else
#define EXP2F exp2f
#endif

// ---------------------------------------------------------------------------
// K1: fused prep + projections (round-1 verified structure).
// grid 256 x 384; block = 4 nodes; thread t -> (t>>7 selects W_l/W_r/W_v,
// t&127 is the output column). W f32 read directly as columns (coalesced
// across lanes at fixed k), converted to f16 in registers. h staged to LDS
// as f16 cooperatively.
// Outputs:
//   Wlh f16 [j][128]                 (o = h*32+d)
//   WrL f16 [4h][8c][1024 j][4 l]    (d = 4c+l; coalesced K2 phase-1 loads)
//   VL  f16 [4h][32 d][1024 j]       (MFMA B-frag: 8 contiguous j at fixed d)
//   AL  f32 [1024 i][4 h]  = sum_d 0.6*a_d*Wlh[i,h,d]   (linear score term)
//   BR  f32 [4 h][1024 j]  = sum_d 0.6*a_d*Wrh[j,h,d]
// ---------------------------------------------------------------------------
__global__ __launch_bounds__(384) void k1_proj(
        const float* __restrict__ Wl, const float* __restrict__ Wr,
        const float* __restrict__ Wv, const float* __restrict__ h,
        const float* __restrict__ a_,
        f16* __restrict__ Wlh, f16* __restrict__ WrL, f16* __restrict__ VL,
        float* __restrict__ AL, float* __restrict__ BR) {
    __shared__ __align__(16) f16 hS[4][128];
    const int t    = threadIdx.x;
    const int i0   = blockIdx.x * 4;
    const int wsel = t >> 7, col = t & 127;
    const int lane = t & 63;

    // stage 4 h-rows to LDS as f16 (512 values over 384 threads)
    for (int e = t; e < 512; e += 384)
        ((f16*)hS)[e] = (f16)h[i0 * 128 + e];

    // load this thread's W column (f32, coalesced across lanes per k) -> f16x2
    const float* W = (wsel == 0) ? Wl : ((wsel == 1) ? Wr : Wv);
    f16x2 w2[64];
    #pragma unroll
    for (int c2 = 0; c2 < 64; c2++) {
        f16x2 v;
        v.x = (f16)W[(2 * c2) * 128 + col];
        v.y = (f16)W[(2 * c2 + 1) * 128 + col];
        w2[c2] = v;
    }
    const float asc = 0.6f * a_[col & 31];
    __syncthreads();

    #pragma unroll
    for (int i = 0; i < 4; i++) {
        const int j = i0 + i;
        const f16x2* hr = (const f16x2*)hS[i];
        float acc = 0.f;
        #pragma unroll
        for (int c2 = 0; c2 < 64; c2++) acc = fdot2f(hr[c2], w2[c2], acc);
        const f16 hv = (f16)acc;
        const int hh = col >> 5, dd = col & 31;
        if (wsel == 0) {
            Wlh[j * 128 + col] = hv;
        } else if (wsel == 1) {
            WrL[((hh * 8 + (dd >> 2)) * 1024 + j) * 4 + (dd & 3)] = hv;
        } else {
            VL[(hh * 32 + dd) * 1024 + j] = hv;
        }
        // linear score terms (f32)
        if (wsel < 2) {
            float part = asc * acc;
            #pragma unroll
            for (int off = 1; off < 32; off <<= 1) part += __shfl_xor(part, off);
            if ((lane & 31) == 0) {
                if (wsel == 0) AL[j * 4 + hh] = part;
                else           BR[hh * 1024 + j] = part;
            }
        }
    }
}

// ---------------------------------------------------------------------------
// K2: fused GATv2 attention + MFMA aggregation + LayerNorm + ReLU.
// grid 256 x 512. Block = 4 nodes i. 8 waves: wave w -> (head hh = w&3,
// j-half = w>>2). LDS 37 KB.
// Score: e[i,j,h] = AL[i,h] + BR[h,j] + sum_d (0.4 a_d)|Wlh+Wrh|
// Phase 1 software-pipelined (static ping-pong A/B buffers): loads for
// jb+1 issue before compute of jb, hiding one L2 latency per iteration.
// ---------------------------------------------------------------------------
__global__ __launch_bounds__(512) void GATv2Layer_84447646974220_kernel(
        const f16* __restrict__ Wlh, const f16* __restrict__ WrL,
        const f16* __restrict__ VL,  const int* __restrict__ adj,
        const float* __restrict__ AL, const float* __restrict__ BR,
        const float* __restrict__ a_, const float* __restrict__ ln_g,
        const float* __restrict__ ln_b, float* __restrict__ out) {

    __shared__ __align__(16) f16 ep[4][4][1024];   // [head][row][j]  32768 B
    __shared__ float aggS[2][4][128];              // [half][row][col] 4096 B
    __shared__ float redM[2][4][4];                // [half][head][row]
    __shared__ float redS[2][4][4];

    const int t    = threadIdx.x;
    const int w    = t >> 6;        // 0..7
    const int lane = t & 63;
    const int hh   = w & 3;         // head
    const int half = w >> 2;        // j-half (0: j<512, 1: j>=512)
    const int i0   = blockIdx.x * 4;

    // per-wave constants: q2 = 0.4*a (f16 pairs), Wl head-slices, AL terms
    f16x2 q2[16];
    #pragma unroll
    for (int d2 = 0; d2 < 16; d2++) {
        f16x2 q; q.x = (f16)(0.4f * a_[2 * d2]); q.y = (f16)(0.4f * a_[2 * d2 + 1]);
        q2[d2] = q;
    }
    f16x2 wl2[4][16];
    float al[4];
    #pragma unroll
    for (int ii = 0; ii < 4; ii++) {
        const f16x2* src = (const f16x2*)(Wlh + (i0 + ii) * 128 + hh * 32);
        #pragma unroll
        for (int c2 = 0; c2 < 16; c2++) wl2[ii][c2] = src[c2];
        al[ii] = AL[(i0 + ii) * 4 + hh];          // wave-uniform broadcast
    }

    // ---- phase 1: scores e[i][j], software-pipelined over jb ----
    float maxE[4];
    #pragma unroll
    for (int ii = 0; ii < 4; ii++) maxE[ii] = -__builtin_inff();

    auto LD = [&](int jb, f16x4 (&wr)[8], int (&am)[4], float &bj) {
        int j = half * 512 + jb * 64 + lane;
        #pragma unroll
        for (int c = 0; c < 8; c++)
            wr[c] = *(const f16x4*)(WrL + ((hh * 8 + c) * 1024 + j) * 4);
        #pragma unroll
        for (int ii = 0; ii < 4; ii++) am[ii] = adj[(i0 + ii) * 1024 + j];
        bj = BR[hh * 1024 + j];
    };
    auto CMP = [&](int jb, const f16x4 (&wr)[8], const int (&am)[4], float bj) {
        int j = half * 512 + jb * 64 + lane;
        float e[4];
        #pragma unroll
        for (int ii = 0; ii < 4; ii++) e[ii] = al[ii];
        #pragma unroll
        for (int c = 0; c < 8; c++) {
            #pragma unroll
            for (int ii = 0; ii < 4; ii++) {
                f16x2 t0 = wl2[ii][2 * c]     + wr[c].lo;
                f16x2 t1 = wl2[ii][2 * c + 1] + wr[c].hi;
                e[ii] = fdot2f(q2[2 * c],     habs2(t0), e[ii]);
                e[ii] = fdot2f(q2[2 * c + 1], habs2(t1), e[ii]);
            }
        }
        #pragma unroll
        for (int ii = 0; ii < 4; ii++) {
            float v = am[ii] ? (e[ii] + bj) : -__builtin_inff();
            maxE[ii] = fmaxf(maxE[ii], v);
            ep[hh][ii][j] = (f16)v;
        }
    };

    f16x4 wrA[8], wrB[8];
    int   amA[4], amB[4];
    float bjA, bjB;

    LD(0, wrA, amA, bjA);
    #pragma unroll 1
    for (int jb = 0; jb < 8; jb += 2) {
        LD(jb + 1, wrB, amB, bjB);
        CMP(jb, wrA, amA, bjA);
        if (jb + 2 < 8) LD(jb + 2, wrA, amA, bjA);
        CMP(jb + 1, wrB, amB, bjB);
    }

    // ---- phase 2: softmax (cross-half max/sum through LDS) ----
    #pragma unroll
    for (int ii = 0; ii < 4; ii++) {
        float M = maxE[ii];
        #pragma unroll
        for (int off = 32; off > 0; off >>= 1) M = fmaxf(M, __shfl_xor(M, off));
        if (lane == 0) redM[half][hh][ii] = M;
    }
    __syncthreads();

    #pragma unroll
    for (int ii = 0; ii < 4; ii++) {
        float M = fmaxf(redM[0][hh][ii], redM[1][hh][ii]);
        f16x8 v0 = *(f16x8*)&ep[hh][ii][half * 512 + lane * 8];
        float pb[8], l = 0.f;
        #pragma unroll
        for (int e = 0; e < 8; e++) pb[e] = EXP2F(((float)v0[e] - M) * LOG2E);
        #pragma unroll
        for (int e = 0; e < 8; e++) { v0[e] = (f16)pb[e]; l += pb[e]; }
        *(f16x8*)&ep[hh][ii][half * 512 + lane * 8] = v0;
        #pragma unroll
        for (int off = 32; off > 0; off >>= 1) l += __shfl_xor(l, off);
        if (lane == 0) redS[half][hh][ii] = l;
    }
    __syncthreads();

    float lr[4];
    #pragma unroll
    for (int ii = 0; ii < 4; ii++)
        lr[ii] = 1.0f / (redS[0][hh][ii] + redS[1][hh][ii]);

    // ---- phase 3: agg = p @ V via MFMA ----
    // A-frag: A[m=lane&15][k=(lane>>4)*8+jj]; rows 4..15 duplicate rows 0..3
    // (m3 = lane&3) — garbage C-rows discarded. B-frag: B[k][n=lane&15] from
    // VL[d=n][j=k] (contiguous j). C/D: col=lane&15, row=(lane>>4)*4+reg.
    // unroll 2: VL loads of tile n+1 overlap MFMA of tile n.
    f32x4 acc0 = {0.f, 0.f, 0.f, 0.f}, acc1 = {0.f, 0.f, 0.f, 0.f};
    const int q8  = (lane >> 4) << 3;
    const int m3  = lane & 3;
    const int n15 = lane & 15;

    #pragma unroll 2
    for (int jt4 = 0; jt4 < 4; jt4++) {
        int jt = half * 4 + jt4;
        #pragma unroll
        for (int kk = 0; kk < 4; kk++) {
            int ko = jt * 128 + kk * 32 + q8;
            f16x8 af = *(const f16x8*)&ep[hh][m3][ko];
            f16x8 b0 = *(const f16x8*)(VL + (hh * 32 + n15) * 1024 + ko);
            f16x8 b1 = *(const f16x8*)(VL + (hh * 32 + 16 + n15) * 1024 + ko);
            acc0 = __builtin_amdgcn_mfma_f32_16x16x32_f16(af, b0, acc0, 0, 0, 0);
            acc1 = __builtin_amdgcn_mfma_f32_16x16x32_f16(af, b1, acc1, 0, 0, 0);
        }
    }

    if (lane < 16) {
        #pragma unroll
        for (int r = 0; r < 4; r++) {
            aggS[half][r][hh * 32 + lane]      = acc0[r] * lr[r];
            aggS[half][r][hh * 32 + 16 + lane] = acc1[r] * lr[r];
        }
    }
    __syncthreads();

    // ---- phase 4: LayerNorm + ReLU (waves 0..3, one node-row each) ----
    if (w < 4) {
        float x0 = aggS[0][w][lane]      + aggS[1][w][lane];
        float x1 = aggS[0][w][lane + 64] + aggS[1][w][lane + 64];
        float s = x0 + x1, sq = x0 * x0 + x1 * x1;
        #pragma unroll
        for (int off = 32; off > 0; off >>= 1) {
            s  += __shfl_xor(s, off);
            sq += __shfl_xor(sq, off);
        }
        float mean = s * (1.f / 128.f);
        float var  = sq * (1.f / 128.f) - mean * mean;
        float rs   = rsqrtf(var + 1e-5f);
        float y0 = fmaxf((x0 - mean) * rs * ln_g[lane]      + ln_b[lane],      0.f);
        float y1 = fmaxf((x1 - mean) * rs * ln_g[lane + 64] + ln_b[lane + 64], 0.f);
        out[(i0 + w) * 128 + lane]      = y0;
        out[(i0 + w) * 128 + 64 + lane] = y1;
    }
}

// ---------------------------------------------------------------------------
extern "C" void kernel_launch(void* const* d_in, const int* in_sizes, int n_in,
                              void* d_out, int out_size, void* d_ws, size_t ws_size,
                              hipStream_t stream) {
    const float* h   = (const float*)d_in[0];
    const int*   adj = (const int*)d_in[1];
    const float* Wl  = (const float*)d_in[2];
    const float* Wr  = (const float*)d_in[3];
    const float* Wv  = (const float*)d_in[4];
    const float* a_  = (const float*)d_in[5];
    const float* g_  = (const float*)d_in[6];
    const float* b_  = (const float*)d_in[7];
    float* out = (float*)d_out;

    char* ws = (char*)d_ws;
    f16*   Wlh = (f16*)(ws);                 // 1024*128 f16    = 262144 B
    f16*   WrL = (f16*)(ws + 262144);        // [4][8][1024][4] = 262144 B
    f16*   VL  = (f16*)(ws + 524288);        // [4][32][1024]   = 262144 B
    float* AL  = (float*)(ws + 786432);      // [1024][4] f32   =  16384 B
    float* BR  = (float*)(ws + 802816);      // [4][1024] f32   =  16384 B

    k1_proj<<<256, 384, 0, stream>>>(Wl, Wr, Wv, h, a_, Wlh, WrL, VL, AL, BR);
    GATv2Layer_84447646974220_kernel<<<256, 512, 0, stream>>>(
        Wlh, WrL, VL, adj, AL, BR, a_, g_, b_, out);
}